// Round 10
// baseline (616.708 us; speedup 1.0000x reference)
//
#include <hip/hip_runtime.h>
#include <hip/hip_bf16.h>
#include <stdint.h>

#define NN 100000
#define NE 1600000
#define DD 128
#define HH 256
#define LL 40

typedef __attribute__((ext_vector_type(8))) short short8;
typedef __attribute__((ext_vector_type(4))) float float4v;
typedef __attribute__((ext_vector_type(8))) float float8v;

__device__ __forceinline__ float bfu_lo(uint32_t u){ union{uint32_t i;float f;}v; v.i=u<<16; return v.f; }
__device__ __forceinline__ float bfu_hi(uint32_t u){ union{uint32_t i;float f;}v; v.i=u&0xFFFF0000u; return v.f; }
__device__ __forceinline__ float bf2f(uint16_t u){ union{uint32_t i;float f;}v; v.i=((uint32_t)u)<<16; return v.f; }
__device__ __forceinline__ uint16_t f2bf(float f){
  union{float f;uint32_t i;}v; v.f=f; uint32_t u=v.i;
  u += 0x7FFFu + ((u>>16)&1u); return (uint16_t)(u>>16);
}
__device__ __forceinline__ void split2(float f, short &hi, short &lo){
  uint16_t h = f2bf(f);
  hi = (short)h;
  lo = (short)f2bf(f - bf2f(h));
}
__device__ __forceinline__ float u2f(uint32_t u){ union{uint32_t i;float f;}v; v.i=u; return v.f; }

// ---------------- preprocessing ----------------

__global__ __launch_bounds__(256) void count_edges(const int* __restrict__ row,
                                                   int* __restrict__ counts, int* __restrict__ rank){
  int e = blockIdx.x*256 + threadIdx.x;
  if (e < NE) rank[e] = atomicAdd(&counts[row[e]], 1);
}

// also emits dinv = rsqrt(deg+1)
__global__ __launch_bounds__(256) void scan_partial(const int* __restrict__ counts,
                                                    int* __restrict__ offs, int* __restrict__ bsums,
                                                    float* __restrict__ dinv){
  __shared__ int sh[256];
  int t = threadIdx.x, i = blockIdx.x*256 + t;
  int v = (i < NN) ? counts[i] : 0;
  if (i < NN) dinv[i] = rsqrtf((float)(v + 1));
  sh[t] = v; __syncthreads();
  for (int d = 1; d < 256; d <<= 1){
    int x = (t >= d) ? sh[t-d] : 0;
    __syncthreads();
    sh[t] += x;
    __syncthreads();
  }
  if (i < NN) offs[i] = sh[t] - v;
  if (t == 255) bsums[blockIdx.x] = sh[255];
}

__global__ __launch_bounds__(512) void scan_block(int* __restrict__ bsums, int nb){
  __shared__ int sh[512];
  int t = threadIdx.x;
  int v = (t < nb) ? bsums[t] : 0;
  sh[t] = v; __syncthreads();
  for (int d = 1; d < 512; d <<= 1){
    int x = (t >= d) ? sh[t-d] : 0;
    __syncthreads();
    sh[t] += x;
    __syncthreads();
  }
  if (t < nb) bsums[t] = sh[t] - v;
}

__global__ __launch_bounds__(256) void scan_add(int* __restrict__ offs, const int* __restrict__ bsums){
  int i = blockIdx.x*256 + threadIdx.x;
  if (i < NN) offs[i] += bsums[blockIdx.x];
  if (i == 0) offs[NN] = NE;
}

__global__ __launch_bounds__(256) void fill_csr(const int* __restrict__ row, const int* __restrict__ col,
                                                const int* __restrict__ rank,
                                                const int* __restrict__ offs,
                                                const float* __restrict__ dinv,
                                                uint2* __restrict__ csr_cw){
  int e = blockIdx.x*256 + threadIdx.x;
  if (e < NE){
    int r = row[e];
    int c = col[e];
    int p = offs[r] + rank[e];
    uint2 v;
    v.x = (uint32_t)c;
    union{float f;uint32_t i;}w; w.f = dinv[c];
    v.y = w.i;
    csr_cw[p] = v;
  }
}

__global__ __launch_bounds__(256) void cvt_bf16(const float2* __restrict__ x, uint32_t* __restrict__ hb){
  int i = blockIdx.x*256 + threadIdx.x;
  if (i < NN*64){
    float2 v = x[i];
    hb[i] = (uint32_t)f2bf(v.x) | ((uint32_t)f2bf(v.y) << 16);
  }
}

// ---------------- weight pre-swizzle (f32 -> bf16 B-fragments) ----------------

template<int KDIM, int NCOL, int NTBP>
__global__ __launch_bounds__(256) void swz(const float* __restrict__ W, uint16_t* __restrict__ Wf){
  constexpr int KB = KDIM / 32;
  constexpr int TOT = KB * NTBP * 512;
  int idx = blockIdx.x*256 + threadIdx.x;
  if (idx >= TOT) return;
  int frag = idx >> 9, r = idx & 511, ln = r >> 3, j = r & 7;
  int kb = frag / NTBP, nt = frag - kb*NTBP;
  int k = kb*32 + ((ln >> 4) << 3) + j;
  int n = nt*16 + (ln & 15);
  float w = (n < NCOL) ? W[k*NCOL + n] : 0.f;
  Wf[idx] = f2bf(w);
}

// ---------------- aggregation: 2 edges per instruction ----------------
// 32 lanes cover one 256 B bf16 row (dwordx2/lane); half 0 handles edge i,
// half 1 handles edge i+1. Accumulators folded across halves at the end.

__global__ __launch_bounds__(256) void agg_b(const uint32_t* __restrict__ hb,
                                             const int* __restrict__ offs,
                                             const uint2* __restrict__ csr_cw,
                                             const float* __restrict__ dinv,
                                             float4* __restrict__ outp){
  const int w = (blockIdx.x*256 + threadIdx.x) >> 6;
  const int lane = threadIdx.x & 63;
  if (w >= NN) return;
  const int half = lane >> 5;
  const uint32_t hl = (uint32_t)(lane & 31);
  const uint32_t hl2 = hl*2u;
  const int s = offs[w], e = offs[w+1];
  const float dr = dinv[w];

  // self row chunk (4 bf16 cols: 4*hl .. 4*hl+3)
  const uint32_t sb = (uint32_t)w*64u + hl2;
  const uint32_t sx = hb[sb], sy = hb[sb+1u];

  float x00=0.f,x01=0.f,x02=0.f,x03=0.f;
  float x10=0.f,x11=0.f,x12=0.f,x13=0.f;
  float x20=0.f,x21=0.f,x22=0.f,x23=0.f;
  float x30=0.f,x31=0.f,x32=0.f,x33=0.f;

  int i = s;
  for (; i + 8 <= e; i += 8){
    int i0 = i + half, i1 = i + 2 + half, i2 = i + 4 + half, i3 = i + 6 + half;
    uint2 p0 = csr_cw[i0], p1 = csr_cw[i1], p2 = csr_cw[i2], p3 = csr_cw[i3];
    uint32_t o0 = p0.x*64u + hl2, o1 = p1.x*64u + hl2;
    uint32_t o2 = p2.x*64u + hl2, o3 = p3.x*64u + hl2;
    uint2 d0 = *(const uint2*)&hb[o0];
    uint2 d1 = *(const uint2*)&hb[o1];
    uint2 d2 = *(const uint2*)&hb[o2];
    uint2 d3 = *(const uint2*)&hb[o3];
    float w0 = u2f(p0.y), w1 = u2f(p1.y), w2 = u2f(p2.y), w3 = u2f(p3.y);
    x00 += w0*bfu_lo(d0.x); x01 += w0*bfu_hi(d0.x); x02 += w0*bfu_lo(d0.y); x03 += w0*bfu_hi(d0.y);
    x10 += w1*bfu_lo(d1.x); x11 += w1*bfu_hi(d1.x); x12 += w1*bfu_lo(d1.y); x13 += w1*bfu_hi(d1.y);
    x20 += w2*bfu_lo(d2.x); x21 += w2*bfu_hi(d2.x); x22 += w2*bfu_lo(d2.y); x23 += w2*bfu_hi(d2.y);
    x30 += w3*bfu_lo(d3.x); x31 += w3*bfu_hi(d3.x); x32 += w3*bfu_lo(d3.y); x33 += w3*bfu_hi(d3.y);
  }
  if (i < e){
    // one predicated 8-wide pass covers the <=7 remaining edges
    int i0 = i + half, i1 = i + 2 + half, i2 = i + 4 + half, i3 = i + 6 + half;
    int c0 = (i0 < e) ? i0 : (e-1);
    int c1 = (i1 < e) ? i1 : (e-1);
    int c2 = (i2 < e) ? i2 : (e-1);
    int c3 = (i3 < e) ? i3 : (e-1);
    uint2 p0 = csr_cw[c0], p1 = csr_cw[c1], p2 = csr_cw[c2], p3 = csr_cw[c3];
    uint32_t o0 = p0.x*64u + hl2, o1 = p1.x*64u + hl2;
    uint32_t o2 = p2.x*64u + hl2, o3 = p3.x*64u + hl2;
    uint2 d0 = *(const uint2*)&hb[o0];
    uint2 d1 = *(const uint2*)&hb[o1];
    uint2 d2 = *(const uint2*)&hb[o2];
    uint2 d3 = *(const uint2*)&hb[o3];
    float w0 = (i0 < e) ? u2f(p0.y) : 0.f;
    float w1 = (i1 < e) ? u2f(p1.y) : 0.f;
    float w2 = (i2 < e) ? u2f(p2.y) : 0.f;
    float w3 = (i3 < e) ? u2f(p3.y) : 0.f;
    x00 += w0*bfu_lo(d0.x); x01 += w0*bfu_hi(d0.x); x02 += w0*bfu_lo(d0.y); x03 += w0*bfu_hi(d0.y);
    x10 += w1*bfu_lo(d1.x); x11 += w1*bfu_hi(d1.x); x12 += w1*bfu_lo(d1.y); x13 += w1*bfu_hi(d1.y);
    x20 += w2*bfu_lo(d2.x); x21 += w2*bfu_hi(d2.x); x22 += w2*bfu_lo(d2.y); x23 += w2*bfu_hi(d2.y);
    x30 += w3*bfu_lo(d3.x); x31 += w3*bfu_hi(d3.x); x32 += w3*bfu_lo(d3.y); x33 += w3*bfu_hi(d3.y);
  }
  // self loop (half 0 only, folded before the cross-half reduce)
  float ws = (half == 0) ? dr : 0.f;
  x00 += ws*bfu_lo(sx); x01 += ws*bfu_hi(sx); x02 += ws*bfu_lo(sy); x03 += ws*bfu_hi(sy);

  float r0 = (x00 + x10) + (x20 + x30);
  float r1 = (x01 + x11) + (x21 + x31);
  float r2 = (x02 + x12) + (x22 + x32);
  float r3 = (x03 + x13) + (x23 + x33);
  r0 += __shfl_xor(r0, 32);
  r1 += __shfl_xor(r1, 32);
  r2 += __shfl_xor(r2, 32);
  r3 += __shfl_xor(r3, 32);
  if (half == 0){
    outp[(size_t)w*32 + hl] = make_float4(r0*dr, r1*dr, r2*dr, r3*dr);
  }
}

// ---------------- square GEMM: H(bf16) <- relu(A(f32) @ W + b) ----------------
// 2 m-tiles per wave (block = 128 rows); W plain bf16; A split hi/lo (2-term).

__global__ __launch_bounds__(256) void gemm_b(const float* __restrict__ A,
                                              const uint16_t* __restrict__ Wf,
                                              const float* __restrict__ bias,
                                              uint16_t* __restrict__ Hout, int M){
  const int lane = threadIdx.x & 63;
  const int wid = threadIdx.x >> 6;
  const int mbase = blockIdx.x*128 + wid*32;
  const int mr = lane & 15;
  const int a0r = (mbase + mr < M) ? (mbase + mr) : (M-1);
  const int a1r = (mbase + 16 + mr < M) ? (mbase + 16 + mr) : (M-1);
  const int ko = (lane >> 4) << 3;

  float4v acc[8][2];
#pragma unroll
  for (int nt = 0; nt < 8; ++nt){ float4v z = {0.f,0.f,0.f,0.f}; acc[nt][0] = z; acc[nt][1] = z; }

#pragma unroll
  for (int kb = 0; kb < 4; ++kb){
    float8v a0 = *(const float8v*)&A[(size_t)a0r*128 + kb*32 + ko];
    float8v a1 = *(const float8v*)&A[(size_t)a1r*128 + kb*32 + ko];
    short8 ah0, al0, ah1, al1;
#pragma unroll
    for (int j = 0; j < 8; ++j){
      short h, l;
      split2(a0[j], h, l); ah0[j] = h; al0[j] = l;
      split2(a1[j], h, l); ah1[j] = h; al1[j] = l;
    }
#pragma unroll
    for (int nt = 0; nt < 8; ++nt){
      short8 bf = *(const short8*)&Wf[(kb*8 + nt)*512 + lane*8];
      acc[nt][0] = __builtin_amdgcn_mfma_f32_16x16x32_bf16(ah0, bf, acc[nt][0], 0, 0, 0);
      acc[nt][0] = __builtin_amdgcn_mfma_f32_16x16x32_bf16(al0, bf, acc[nt][0], 0, 0, 0);
      acc[nt][1] = __builtin_amdgcn_mfma_f32_16x16x32_bf16(ah1, bf, acc[nt][1], 0, 0, 0);
      acc[nt][1] = __builtin_amdgcn_mfma_f32_16x16x32_bf16(al1, bf, acc[nt][1], 0, 0, 0);
    }
  }

  const int col = lane & 15;
  const int rb  = (lane >> 4) * 4;
#pragma unroll
  for (int nt = 0; nt < 8; ++nt){
    int n = nt*16 + col;
    float bv = bias[n];
#pragma unroll
    for (int mt = 0; mt < 2; ++mt){
#pragma unroll
      for (int r = 0; r < 4; ++r){
        int m = mbase + mt*16 + rb + r;
        if (m < M){
          float v = acc[nt][mt][r] + bv;
          Hout[(size_t)m*128 + n] = f2bf(v > 0.f ? v : 0.f);
        }
      }
    }
  }
}

// ---------------- fused MLP: 2 m-tiles/wave, bf16 weights (1-term), stride-260 LDS ----------------

#define HS 260

__global__ __launch_bounds__(256) void mlp_fused(const uint16_t* __restrict__ Hb,
                                                 const uint16_t* __restrict__ W1f,
                                                 const float* __restrict__ b1,
                                                 const uint16_t* __restrict__ W2f,
                                                 const float* __restrict__ b2,
                                                 float* __restrict__ out, int M){
  __shared__ uint16_t hid[128*HS];
  const int lane = threadIdx.x & 63;
  const int wid = threadIdx.x >> 6;
  const int mbase = blockIdx.x*128 + wid*32;
  const int mr = lane & 15;
  const int a0r = (mbase + mr < M) ? (mbase + mr) : (M-1);
  const int a1r = (mbase + 16 + mr < M) ? (mbase + 16 + mr) : (M-1);
  const int ko = (lane >> 4) << 3;
  const int col = lane & 15;
  const int rb  = (lane >> 4) * 4;

  float4v acc1[16][2];
#pragma unroll
  for (int nt = 0; nt < 16; ++nt){ float4v z = {0.f,0.f,0.f,0.f}; acc1[nt][0] = z; acc1[nt][1] = z; }
#pragma unroll
  for (int kb = 0; kb < 4; ++kb){
    short8 af0 = *(const short8*)&Hb[(size_t)a0r*128 + kb*32 + ko];
    short8 af1 = *(const short8*)&Hb[(size_t)a1r*128 + kb*32 + ko];
#pragma unroll
    for (int nt = 0; nt < 16; ++nt){
      short8 bf = *(const short8*)&W1f[(kb*16 + nt)*512 + lane*8];
      acc1[nt][0] = __builtin_amdgcn_mfma_f32_16x16x32_bf16(af0, bf, acc1[nt][0], 0, 0, 0);
      acc1[nt][1] = __builtin_amdgcn_mfma_f32_16x16x32_bf16(af1, bf, acc1[nt][1], 0, 0, 0);
    }
  }
#pragma unroll
  for (int nt = 0; nt < 16; ++nt){
    float bv = b1[nt*16 + col];
#pragma unroll
    for (int mt = 0; mt < 2; ++mt){
#pragma unroll
      for (int r = 0; r < 4; ++r){
        float v = acc1[nt][mt][r] + bv;
        v = v > 0.f ? v : 0.f;
        hid[(wid*32 + mt*16 + rb + r)*HS + nt*16 + col] = f2bf(v);
      }
    }
  }
  __syncthreads();

  float4v acc2[3][2];
#pragma unroll
  for (int nt = 0; nt < 3; ++nt){ float4v z = {0.f,0.f,0.f,0.f}; acc2[nt][0] = z; acc2[nt][1] = z; }
#pragma unroll
  for (int kb = 0; kb < 8; ++kb){
    short8 a0 = *(const short8*)&hid[(wid*32 + mr)*HS + kb*32 + ko];
    short8 a1 = *(const short8*)&hid[(wid*32 + 16 + mr)*HS + kb*32 + ko];
#pragma unroll
    for (int nt = 0; nt < 3; ++nt){
      short8 bf = *(const short8*)&W2f[(kb*3 + nt)*512 + lane*8];
      acc2[nt][0] = __builtin_amdgcn_mfma_f32_16x16x32_bf16(a0, bf, acc2[nt][0], 0, 0, 0);
      acc2[nt][1] = __builtin_amdgcn_mfma_f32_16x16x32_bf16(a1, bf, acc2[nt][1], 0, 0, 0);
    }
  }
#pragma unroll
  for (int nt = 0; nt < 3; ++nt){
    int n = nt*16 + col;
    if (n < LL){
      float bv = b2[n];
#pragma unroll
      for (int mt = 0; mt < 2; ++mt){
#pragma unroll
        for (int r = 0; r < 4; ++r){
          int m = mbase + mt*16 + rb + r;
          if (m < M) out[(size_t)m*LL + n] = acc2[nt][mt][r] + bv;
        }
      }
    }
  }
}

// ---------------- launch ----------------

extern "C" void kernel_launch(void* const* d_in, const int* in_sizes, int n_in,
                              void* d_out, int out_size, void* d_ws, size_t ws_size,
                              hipStream_t stream){
  const float* x   = (const float*)d_in[0];
  const int*   ei  = (const int*)d_in[1];
  const float* W0  = (const float*)d_in[2];
  const float* b0  = (const float*)d_in[3];
  const float* W1  = (const float*)d_in[4];
  const float* b1  = (const float*)d_in[5];
  const float* W2  = (const float*)d_in[6];
  const float* b2  = (const float*)d_in[7];
  const float* Wm1 = (const float*)d_in[8];
  const float* bm1 = (const float*)d_in[9];
  const float* Wm2 = (const float*)d_in[10];
  const float* bm2 = (const float*)d_in[11];
  const int* row = ei;
  const int* col = ei + NE;

  char* ws = (char*)d_ws;
  size_t off = 0;
  auto alloc = [&](size_t bytes)->void*{
    void* p = ws + off;
    off += (bytes + 255) & ~(size_t)255;
    return p;
  };
  int*      counts  = (int*)alloc((size_t)NN*4);
  int*      offs    = (int*)alloc(((size_t)NN+1)*4);
  int*      bsums   = (int*)alloc(1024*4);
  float*    dinv    = (float*)alloc((size_t)NN*4);
  int*      rank    = (int*)alloc((size_t)NE*4);
  uint2*    csr_cw  = (uint2*)alloc((size_t)NE*8);
  uint16_t* W0f     = (uint16_t*)alloc(4*8*512*2);
  uint16_t* W1f     = (uint16_t*)alloc(4*8*512*2);
  uint16_t* W2f     = (uint16_t*)alloc(4*8*512*2);
  uint16_t* Wm1f    = (uint16_t*)alloc(4*16*512*2);
  uint16_t* Wm2f    = (uint16_t*)alloc(8*3*512*2);
  uint16_t* hb      = (uint16_t*)alloc((size_t)NN*DD*2);
  float*    A       = (float*)alloc((size_t)NN*DD*4);

  hipMemsetAsync(counts, 0, (size_t)NN*4, stream);
  count_edges<<<(NE+255)/256, 256, 0, stream>>>(row, counts, rank);
  const int NB = (NN+255)/256;
  scan_partial<<<NB, 256, 0, stream>>>(counts, offs, bsums, dinv);
  scan_block<<<1, 512, 0, stream>>>(bsums, NB);
  scan_add<<<NB, 256, 0, stream>>>(offs, bsums);
  fill_csr<<<(NE+255)/256, 256, 0, stream>>>(row, col, rank, offs, dinv, csr_cw);

  swz<128,128,8><<<(4*8*512+255)/256, 256, 0, stream>>>(W0, W0f);
  swz<128,128,8><<<(4*8*512+255)/256, 256, 0, stream>>>(W1, W1f);
  swz<128,128,8><<<(4*8*512+255)/256, 256, 0, stream>>>(W2, W2f);
  swz<128,256,16><<<(4*16*512+255)/256, 256, 0, stream>>>(Wm1, Wm1f);
  swz<256,40,3><<<(8*3*512+255)/256, 256, 0, stream>>>(Wm2, Wm2f);

  cvt_bf16<<<(NN*64+255)/256, 256, 0, stream>>>((const float2*)x, (uint32_t*)hb);

  const int AGG_BLOCKS = (NN*64 + 255)/256;
  const int GB128 = (NN + 127)/128;

  agg_b<<<AGG_BLOCKS, 256, 0, stream>>>((const uint32_t*)hb, offs, csr_cw, dinv, (float4*)A);
  gemm_b<<<GB128, 256, 0, stream>>>(A, W0f, b0, hb, NN);

  agg_b<<<AGG_BLOCKS, 256, 0, stream>>>((const uint32_t*)hb, offs, csr_cw, dinv, (float4*)A);
  gemm_b<<<GB128, 256, 0, stream>>>(A, W1f, b1, hb, NN);

  agg_b<<<AGG_BLOCKS, 256, 0, stream>>>((const uint32_t*)hb, offs, csr_cw, dinv, (float4*)A);
  gemm_b<<<GB128, 256, 0, stream>>>(A, W2f, b2, hb, NN);

  mlp_fused<<<GB128, 256, 0, stream>>>(hb, Wm1f, bm1, Wm2f, bm2, (float*)d_out, NN);
}

// Round 11
// 507.450 us; speedup vs baseline: 1.2153x; 1.2153x over previous
//
#include <hip/hip_runtime.h>
#include <hip/hip_bf16.h>
#include <stdint.h>

#define NN 100000
#define NE 1600000
#define DD 128
#define HH 256
#define LL 40

typedef __attribute__((ext_vector_type(8))) short short8;
typedef __attribute__((ext_vector_type(4))) float float4v;

__device__ __forceinline__ float bfu_lo(uint32_t u){ union{uint32_t i;float f;}v; v.i=u<<16; return v.f; }
__device__ __forceinline__ float bfu_hi(uint32_t u){ union{uint32_t i;float f;}v; v.i=u&0xFFFF0000u; return v.f; }
__device__ __forceinline__ float bf2f(uint16_t u){ union{uint32_t i;float f;}v; v.i=((uint32_t)u)<<16; return v.f; }
__device__ __forceinline__ uint16_t f2bf(float f){
  union{float f;uint32_t i;}v; v.f=f; uint32_t u=v.i;
  u += 0x7FFFu + ((u>>16)&1u); return (uint16_t)(u>>16);
}
__device__ __forceinline__ void split2(float f, short &hi, short &lo){
  uint16_t h = f2bf(f);
  hi = (short)h;
  lo = (short)f2bf(f - bf2f(h));
}
__device__ __forceinline__ float u2f(uint32_t u){ union{uint32_t i;float f;}v; v.i=u; return v.f; }

// ---------------- preprocessing ----------------

__global__ __launch_bounds__(256) void count_edges(const int* __restrict__ row,
                                                   int* __restrict__ counts, uint16_t* __restrict__ rank){
  int e = blockIdx.x*256 + threadIdx.x;
  if (e < NE) rank[e] = (uint16_t)atomicAdd(&counts[row[e]], 1);
}

// also emits dinv = rsqrt(deg+1)
__global__ __launch_bounds__(256) void scan_partial(const int* __restrict__ counts,
                                                    int* __restrict__ offs, int* __restrict__ bsums,
                                                    float* __restrict__ dinv){
  __shared__ int sh[256];
  int t = threadIdx.x, i = blockIdx.x*256 + t;
  int v = (i < NN) ? counts[i] : 0;
  if (i < NN) dinv[i] = rsqrtf((float)(v + 1));
  sh[t] = v; __syncthreads();
  for (int d = 1; d < 256; d <<= 1){
    int x = (t >= d) ? sh[t-d] : 0;
    __syncthreads();
    sh[t] += x;
    __syncthreads();
  }
  if (i < NN) offs[i] = sh[t] - v;
  if (t == 255) bsums[blockIdx.x] = sh[255];
}

__global__ __launch_bounds__(512) void scan_block(int* __restrict__ bsums, int nb){
  __shared__ int sh[512];
  int t = threadIdx.x;
  int v = (t < nb) ? bsums[t] : 0;
  sh[t] = v; __syncthreads();
  for (int d = 1; d < 512; d <<= 1){
    int x = (t >= d) ? sh[t-d] : 0;
    __syncthreads();
    sh[t] += x;
    __syncthreads();
  }
  if (t < nb) bsums[t] = sh[t] - v;
}

__global__ __launch_bounds__(256) void scan_add(int* __restrict__ offs, const int* __restrict__ bsums){
  int i = blockIdx.x*256 + threadIdx.x;
  if (i < NN) offs[i] += bsums[blockIdx.x];
  if (i == 0) offs[NN] = NE;
}

__global__ __launch_bounds__(256) void fill_csr(const int* __restrict__ row, const int* __restrict__ col,
                                                const uint16_t* __restrict__ rank,
                                                const int* __restrict__ offs,
                                                const float* __restrict__ dinv,
                                                uint2* __restrict__ csr_cw){
  int e = blockIdx.x*256 + threadIdx.x;
  if (e < NE){
    int r = row[e];
    int c = col[e];
    int p = offs[r] + (int)rank[e];
    uint2 v;
    v.x = (uint32_t)c;
    union{float f;uint32_t i;}w; w.f = dinv[c];
    v.y = w.i;
    csr_cw[p] = v;
  }
}

__global__ __launch_bounds__(256) void cvt_bf16(const float2* __restrict__ x, uint32_t* __restrict__ hb){
  int i = blockIdx.x*256 + threadIdx.x;
  if (i < NN*64){
    float2 v = x[i];
    hb[i] = (uint32_t)f2bf(v.x) | ((uint32_t)f2bf(v.y) << 16);
  }
}

// ---------------- weight pre-swizzle (f32 -> bf16 B-fragments) ----------------

template<int KDIM, int NCOL, int NTBP>
__global__ __launch_bounds__(256) void swz(const float* __restrict__ W, uint16_t* __restrict__ Wf){
  constexpr int KB = KDIM / 32;
  constexpr int TOT = KB * NTBP * 512;
  int idx = blockIdx.x*256 + threadIdx.x;
  if (idx >= TOT) return;
  int frag = idx >> 9, r = idx & 511, ln = r >> 3, j = r & 7;
  int kb = frag / NTBP, nt = frag - kb*NTBP;
  int k = kb*32 + ((ln >> 4) << 3) + j;
  int n = nt*16 + (ln & 15);
  float w = (n < NCOL) ? W[k*NCOL + n] : 0.f;
  Wf[idx] = f2bf(w);
}

// ---------------- fused layer: Hout(bf16) = relu( (A_norm @ hb) @ W + b ) ----------------
// Block = 16 rows. Phase 1: each wave aggregates 4 rows (R8-proven 8-deep loop,
// one wave-row per edge gather) into a padded f32 LDS tile. Phase 2: each wave
// computes 2 n-tiles of the 16x128 MFMA (2-term split-A), writes bf16.
// Hout must be a DIFFERENT buffer than hb (other blocks gather from hb).

__global__ __launch_bounds__(256) void agg_gemm(const uint32_t* __restrict__ hb,
                                                const int* __restrict__ offs,
                                                const uint2* __restrict__ csr_cw,
                                                const float* __restrict__ dinv,
                                                const uint16_t* __restrict__ Wf,
                                                const float* __restrict__ bias,
                                                uint16_t* __restrict__ Hout){
  __shared__ float lds[16*129];
  const int lane = threadIdx.x & 63;
  const int wid = threadIdx.x >> 6;
  const int rbase = blockIdx.x*16;   // NN % 16 == 0, all rows valid

  // ---- phase 1: aggregate rows rbase+4*wid .. +3 ----
  for (int rl = wid*4; rl < wid*4 + 4; ++rl){
    const int w = rbase + rl;
    const int s = offs[w], e = offs[w+1];
    const float dr = dinv[w];
    const uint32_t us = hb[(size_t)w*64 + lane];

    float a0=0.f,a1=0.f,b0=0.f,b1=0.f,c0=0.f,c1=0.f,d0=0.f,d1=0.f;
    float e0=0.f,e1=0.f,f0=0.f,f1=0.f,g0=0.f,g1=0.f,h0=0.f,h1=0.f;
    int i = s;
    for (; i + 8 <= e; i += 8){
      uint2 p0=csr_cw[i],  p1=csr_cw[i+1], p2=csr_cw[i+2], p3=csr_cw[i+3];
      uint2 p4=csr_cw[i+4],p5=csr_cw[i+5], p6=csr_cw[i+6], p7=csr_cw[i+7];
      uint32_t u0=hb[(size_t)p0.x*64+lane], u1=hb[(size_t)p1.x*64+lane];
      uint32_t u2=hb[(size_t)p2.x*64+lane], u3=hb[(size_t)p3.x*64+lane];
      uint32_t u4=hb[(size_t)p4.x*64+lane], u5=hb[(size_t)p5.x*64+lane];
      uint32_t u6=hb[(size_t)p6.x*64+lane], u7=hb[(size_t)p7.x*64+lane];
      a0 += u2f(p0.y)*bfu_lo(u0); a1 += u2f(p0.y)*bfu_hi(u0);
      b0 += u2f(p1.y)*bfu_lo(u1); b1 += u2f(p1.y)*bfu_hi(u1);
      c0 += u2f(p2.y)*bfu_lo(u2); c1 += u2f(p2.y)*bfu_hi(u2);
      d0 += u2f(p3.y)*bfu_lo(u3); d1 += u2f(p3.y)*bfu_hi(u3);
      e0 += u2f(p4.y)*bfu_lo(u4); e1 += u2f(p4.y)*bfu_hi(u4);
      f0 += u2f(p5.y)*bfu_lo(u5); f1 += u2f(p5.y)*bfu_hi(u5);
      g0 += u2f(p6.y)*bfu_lo(u6); g1 += u2f(p6.y)*bfu_hi(u6);
      h0 += u2f(p7.y)*bfu_lo(u7); h1 += u2f(p7.y)*bfu_hi(u7);
    }
    if (i + 4 <= e){
      uint2 p0=csr_cw[i], p1=csr_cw[i+1], p2=csr_cw[i+2], p3=csr_cw[i+3];
      uint32_t u0=hb[(size_t)p0.x*64+lane], u1=hb[(size_t)p1.x*64+lane];
      uint32_t u2=hb[(size_t)p2.x*64+lane], u3=hb[(size_t)p3.x*64+lane];
      a0 += u2f(p0.y)*bfu_lo(u0); a1 += u2f(p0.y)*bfu_hi(u0);
      b0 += u2f(p1.y)*bfu_lo(u1); b1 += u2f(p1.y)*bfu_hi(u1);
      c0 += u2f(p2.y)*bfu_lo(u2); c1 += u2f(p2.y)*bfu_hi(u2);
      d0 += u2f(p3.y)*bfu_lo(u3); d1 += u2f(p3.y)*bfu_hi(u3);
      i += 4;
    }
    for (; i < e; ++i){
      uint2 p = csr_cw[i];
      uint32_t u = hb[(size_t)p.x*64 + lane];
      a0 += u2f(p.y)*bfu_lo(u); a1 += u2f(p.y)*bfu_hi(u);
    }
    float r0 = (((a0+b0)+(c0+d0)) + ((e0+f0)+(g0+h0))) + dr*bfu_lo(us);
    float r1 = (((a1+b1)+(c1+d1)) + ((e1+f1)+(g1+h1))) + dr*bfu_hi(us);
    lds[rl*129 + 2*lane]     = r0*dr;
    lds[rl*129 + 2*lane + 1] = r1*dr;
  }
  __syncthreads();

  // ---- phase 2: 16x128 GEMM tile; this wave covers n-tiles 2*wid, 2*wid+1 ----
  const int mr = lane & 15;
  const int ko = (lane >> 4) << 3;
  float4v acc[2];
  { float4v z = {0.f,0.f,0.f,0.f}; acc[0] = z; acc[1] = z; }
#pragma unroll
  for (int kb = 0; kb < 4; ++kb){
    short8 ah, al;
#pragma unroll
    for (int j = 0; j < 8; ++j){
      float f = lds[mr*129 + kb*32 + ko + j];
      short h, l; split2(f, h, l); ah[j] = h; al[j] = l;
    }
#pragma unroll
    for (int t = 0; t < 2; ++t){
      int nt = wid*2 + t;
      short8 bf = *(const short8*)&Wf[(kb*8 + nt)*512 + lane*8];
      acc[t] = __builtin_amdgcn_mfma_f32_16x16x32_bf16(ah, bf, acc[t], 0, 0, 0);
      acc[t] = __builtin_amdgcn_mfma_f32_16x16x32_bf16(al, bf, acc[t], 0, 0, 0);
    }
  }
  const int col = lane & 15;
  const int rb  = (lane >> 4) * 4;
#pragma unroll
  for (int t = 0; t < 2; ++t){
    int n = (wid*2 + t)*16 + col;
    float bv = bias[n];
#pragma unroll
    for (int r = 0; r < 4; ++r){
      int m = rbase + rb + r;
      float v = acc[t][r] + bv;
      Hout[(size_t)m*128 + n] = f2bf(v > 0.f ? v : 0.f);
    }
  }
}

// ---------------- fused MLP: 2 m-tiles/wave, bf16 weights (1-term), stride-260 LDS ----------------

#define HS 260

__global__ __launch_bounds__(256) void mlp_fused(const uint16_t* __restrict__ Hb,
                                                 const uint16_t* __restrict__ W1f,
                                                 const float* __restrict__ b1,
                                                 const uint16_t* __restrict__ W2f,
                                                 const float* __restrict__ b2,
                                                 float* __restrict__ out, int M){
  __shared__ uint16_t hid[128*HS];
  const int lane = threadIdx.x & 63;
  const int wid = threadIdx.x >> 6;
  const int mbase = blockIdx.x*128 + wid*32;
  const int mr = lane & 15;
  const int a0r = (mbase + mr < M) ? (mbase + mr) : (M-1);
  const int a1r = (mbase + 16 + mr < M) ? (mbase + 16 + mr) : (M-1);
  const int ko = (lane >> 4) << 3;
  const int col = lane & 15;
  const int rb  = (lane >> 4) * 4;

  float4v acc1[16][2];
#pragma unroll
  for (int nt = 0; nt < 16; ++nt){ float4v z = {0.f,0.f,0.f,0.f}; acc1[nt][0] = z; acc1[nt][1] = z; }
#pragma unroll
  for (int kb = 0; kb < 4; ++kb){
    short8 af0 = *(const short8*)&Hb[(size_t)a0r*128 + kb*32 + ko];
    short8 af1 = *(const short8*)&Hb[(size_t)a1r*128 + kb*32 + ko];
#pragma unroll
    for (int nt = 0; nt < 16; ++nt){
      short8 bf = *(const short8*)&W1f[(kb*16 + nt)*512 + lane*8];
      acc1[nt][0] = __builtin_amdgcn_mfma_f32_16x16x32_bf16(af0, bf, acc1[nt][0], 0, 0, 0);
      acc1[nt][1] = __builtin_amdgcn_mfma_f32_16x16x32_bf16(af1, bf, acc1[nt][1], 0, 0, 0);
    }
  }
#pragma unroll
  for (int nt = 0; nt < 16; ++nt){
    float bv = b1[nt*16 + col];
#pragma unroll
    for (int mt = 0; mt < 2; ++mt){
#pragma unroll
      for (int r = 0; r < 4; ++r){
        float v = acc1[nt][mt][r] + bv;
        v = v > 0.f ? v : 0.f;
        hid[(wid*32 + mt*16 + rb + r)*HS + nt*16 + col] = f2bf(v);
      }
    }
  }
  __syncthreads();

  float4v acc2[3][2];
#pragma unroll
  for (int nt = 0; nt < 3; ++nt){ float4v z = {0.f,0.f,0.f,0.f}; acc2[nt][0] = z; acc2[nt][1] = z; }
#pragma unroll
  for (int kb = 0; kb < 8; ++kb){
    short8 a0 = *(const short8*)&hid[(wid*32 + mr)*HS + kb*32 + ko];
    short8 a1 = *(const short8*)&hid[(wid*32 + 16 + mr)*HS + kb*32 + ko];
#pragma unroll
    for (int nt = 0; nt < 3; ++nt){
      short8 bf = *(const short8*)&W2f[(kb*3 + nt)*512 + lane*8];
      acc2[nt][0] = __builtin_amdgcn_mfma_f32_16x16x32_bf16(a0, bf, acc2[nt][0], 0, 0, 0);
      acc2[nt][1] = __builtin_amdgcn_mfma_f32_16x16x32_bf16(a1, bf, acc2[nt][1], 0, 0, 0);
    }
  }
#pragma unroll
  for (int nt = 0; nt < 3; ++nt){
    int n = nt*16 + col;
    if (n < LL){
      float bv = b2[n];
#pragma unroll
      for (int mt = 0; mt < 2; ++mt){
#pragma unroll
        for (int r = 0; r < 4; ++r){
          int m = mbase + mt*16 + rb + r;
          if (m < M) out[(size_t)m*LL + n] = acc2[nt][mt][r] + bv;
        }
      }
    }
  }
}

// ---------------- launch ----------------

extern "C" void kernel_launch(void* const* d_in, const int* in_sizes, int n_in,
                              void* d_out, int out_size, void* d_ws, size_t ws_size,
                              hipStream_t stream){
  const float* x   = (const float*)d_in[0];
  const int*   ei  = (const int*)d_in[1];
  const float* W0  = (const float*)d_in[2];
  const float* b0  = (const float*)d_in[3];
  const float* W1  = (const float*)d_in[4];
  const float* b1  = (const float*)d_in[5];
  const float* W2  = (const float*)d_in[6];
  const float* b2  = (const float*)d_in[7];
  const float* Wm1 = (const float*)d_in[8];
  const float* bm1 = (const float*)d_in[9];
  const float* Wm2 = (const float*)d_in[10];
  const float* bm2 = (const float*)d_in[11];
  const int* row = ei;
  const int* col = ei + NE;

  char* ws = (char*)d_ws;
  size_t off = 0;
  auto alloc = [&](size_t bytes)->void*{
    void* p = ws + off;
    off += (bytes + 255) & ~(size_t)255;
    return p;
  };
  int*      counts  = (int*)alloc((size_t)NN*4);
  int*      offs    = (int*)alloc(((size_t)NN+1)*4);
  int*      bsums   = (int*)alloc(1024*4);
  float*    dinv    = (float*)alloc((size_t)NN*4);
  uint16_t* rank    = (uint16_t*)alloc((size_t)NE*2);
  uint2*    csr_cw  = (uint2*)alloc((size_t)NE*8);
  uint16_t* W0f     = (uint16_t*)alloc(4*8*512*2);
  uint16_t* W1f     = (uint16_t*)alloc(4*8*512*2);
  uint16_t* W2f     = (uint16_t*)alloc(4*8*512*2);
  uint16_t* Wm1f    = (uint16_t*)alloc(4*16*512*2);
  uint16_t* Wm2f    = (uint16_t*)alloc(8*3*512*2);
  uint16_t* hb      = (uint16_t*)alloc((size_t)NN*DD*2);
  uint16_t* hb2     = (uint16_t*)alloc((size_t)NN*DD*2);

  hipMemsetAsync(counts, 0, (size_t)NN*4, stream);
  count_edges<<<(NE+255)/256, 256, 0, stream>>>(row, counts, rank);
  const int NB = (NN+255)/256;
  scan_partial<<<NB, 256, 0, stream>>>(counts, offs, bsums, dinv);
  scan_block<<<1, 512, 0, stream>>>(bsums, NB);
  scan_add<<<NB, 256, 0, stream>>>(offs, bsums);
  fill_csr<<<(NE+255)/256, 256, 0, stream>>>(row, col, rank, offs, dinv, csr_cw);

  swz<128,128,8><<<(4*8*512+255)/256, 256, 0, stream>>>(W0, W0f);
  swz<128,128,8><<<(4*8*512+255)/256, 256, 0, stream>>>(W1, W1f);
  swz<128,128,8><<<(4*8*512+255)/256, 256, 0, stream>>>(W2, W2f);
  swz<128,256,16><<<(4*16*512+255)/256, 256, 0, stream>>>(Wm1, Wm1f);
  swz<256,40,3><<<(8*3*512+255)/256, 256, 0, stream>>>(Wm2, Wm2f);

  cvt_bf16<<<(NN*64+255)/256, 256, 0, stream>>>((const float2*)x, (uint32_t*)hb);

  const int LB = NN/16;   // 6250 blocks, 16 rows each

  agg_gemm<<<LB, 256, 0, stream>>>((const uint32_t*)hb,  offs, csr_cw, dinv, W0f, b0, hb2);
  agg_gemm<<<LB, 256, 0, stream>>>((const uint32_t*)hb2, offs, csr_cw, dinv, W1f, b1, hb);
  agg_gemm<<<LB, 256, 0, stream>>>((const uint32_t*)hb,  offs, csr_cw, dinv, W2f, b2, hb2);

  const int GB128 = (NN + 127)/128;
  mlp_fused<<<GB128, 256, 0, stream>>>(hb2, Wm1f, bm1, Wm2f, bm2, (float*)d_out, NN);
}

// Round 12
// 505.525 us; speedup vs baseline: 1.2199x; 1.0038x over previous
//
#include <hip/hip_runtime.h>
#include <hip/hip_bf16.h>
#include <stdint.h>

#define NN 100000
#define NE 1600000
#define DD 128
#define HH 256
#define LL 40

typedef __attribute__((ext_vector_type(8))) short short8;
typedef __attribute__((ext_vector_type(4))) float float4v;

__device__ __forceinline__ float bfu_lo(uint32_t u){ union{uint32_t i;float f;}v; v.i=u<<16; return v.f; }
__device__ __forceinline__ float bfu_hi(uint32_t u){ union{uint32_t i;float f;}v; v.i=u&0xFFFF0000u; return v.f; }
__device__ __forceinline__ float bf2f(uint16_t u){ union{uint32_t i;float f;}v; v.i=((uint32_t)u)<<16; return v.f; }
__device__ __forceinline__ uint16_t f2bf(float f){
  union{float f;uint32_t i;}v; v.f=f; uint32_t u=v.i;
  u += 0x7FFFu + ((u>>16)&1u); return (uint16_t)(u>>16);
}
__device__ __forceinline__ void split2(float f, short &hi, short &lo){
  uint16_t h = f2bf(f);
  hi = (short)h;
  lo = (short)f2bf(f - bf2f(h));
}
__device__ __forceinline__ float u2f(uint32_t u){ union{uint32_t i;float f;}v; v.i=u; return v.f; }

// ---------------- prep: zero counts + cvt x->bf16 + all weight swizzles ----------------
// segments: [0,NN) counts=0 | [NN, NN+6.4M) cvt | then W0f/W1f/W2f/Wm1f/Wm2f fragments

__device__ __forceinline__ void swz_one(const float* __restrict__ W, uint16_t* __restrict__ Wf,
                                        int idx, int NCOL, int NTBP){
  int frag = idx >> 9, r = idx & 511, ln = r >> 3, j = r & 7;
  int kb = frag / NTBP, nt = frag - kb*NTBP;
  int k = kb*32 + ((ln >> 4) << 3) + j;
  int n = nt*16 + (ln & 15);
  float w = (n < NCOL) ? W[k*NCOL + n] : 0.f;
  Wf[idx] = f2bf(w);
}

#define PREP_CVT   (NN)
#define PREP_W0    (PREP_CVT + NN*64)
#define PREP_W1    (PREP_W0 + 16384)
#define PREP_W2    (PREP_W1 + 16384)
#define PREP_WM1   (PREP_W2 + 16384)
#define PREP_WM2   (PREP_WM1 + 32768)
#define PREP_TOT   (PREP_WM2 + 12288)

__global__ __launch_bounds__(256) void prep(const float2* __restrict__ x,
                                            int* __restrict__ counts, uint32_t* __restrict__ hb,
                                            const float* __restrict__ W0, uint16_t* __restrict__ W0f,
                                            const float* __restrict__ W1, uint16_t* __restrict__ W1f,
                                            const float* __restrict__ W2, uint16_t* __restrict__ W2f,
                                            const float* __restrict__ Wm1, uint16_t* __restrict__ Wm1f,
                                            const float* __restrict__ Wm2, uint16_t* __restrict__ Wm2f){
  int idx = blockIdx.x*256 + threadIdx.x;
  if (idx < PREP_CVT){
    counts[idx] = 0;
  } else if (idx < PREP_W0){
    int i = idx - PREP_CVT;
    float2 v = x[i];
    hb[i] = (uint32_t)f2bf(v.x) | ((uint32_t)f2bf(v.y) << 16);
  } else if (idx < PREP_W1){
    swz_one(W0, W0f, idx - PREP_W0, 128, 8);
  } else if (idx < PREP_W2){
    swz_one(W1, W1f, idx - PREP_W1, 128, 8);
  } else if (idx < PREP_WM1){
    swz_one(W2, W2f, idx - PREP_W2, 128, 8);
  } else if (idx < PREP_WM2){
    swz_one(Wm1, Wm1f, idx - PREP_WM1, 256, 16);
  } else if (idx < PREP_TOT){
    swz_one(Wm2, Wm2f, idx - PREP_WM2, 40, 3);
  }
}

// ---------------- preprocessing ----------------

__global__ __launch_bounds__(256) void count_edges(const int* __restrict__ row,
                                                   int* __restrict__ counts, uint16_t* __restrict__ rank){
  int e2 = blockIdx.x*256 + threadIdx.x;
  if (e2 < NE/2){
    int2 r2 = ((const int2*)row)[e2];
    uint16_t a = (uint16_t)atomicAdd(&counts[r2.x], 1);
    uint16_t b = (uint16_t)atomicAdd(&counts[r2.y], 1);
    ((ushort2*)rank)[e2] = make_ushort2(a, b);
  }
}

// also emits dinv = rsqrt(deg+1)
__global__ __launch_bounds__(256) void scan_partial(const int* __restrict__ counts,
                                                    int* __restrict__ offs, int* __restrict__ bsums,
                                                    float* __restrict__ dinv){
  __shared__ int sh[256];
  int t = threadIdx.x, i = blockIdx.x*256 + t;
  int v = (i < NN) ? counts[i] : 0;
  if (i < NN) dinv[i] = rsqrtf((float)(v + 1));
  sh[t] = v; __syncthreads();
  for (int d = 1; d < 256; d <<= 1){
    int x = (t >= d) ? sh[t-d] : 0;
    __syncthreads();
    sh[t] += x;
    __syncthreads();
  }
  if (i < NN) offs[i] = sh[t] - v;
  if (t == 255) bsums[blockIdx.x] = sh[255];
}

__global__ __launch_bounds__(512) void scan_block(int* __restrict__ bsums, int nb){
  __shared__ int sh[512];
  int t = threadIdx.x;
  int v = (t < nb) ? bsums[t] : 0;
  sh[t] = v; __syncthreads();
  for (int d = 1; d < 512; d <<= 1){
    int x = (t >= d) ? sh[t-d] : 0;
    __syncthreads();
    sh[t] += x;
    __syncthreads();
  }
  if (t < nb) bsums[t] = sh[t] - v;
}

__global__ __launch_bounds__(256) void scan_add(int* __restrict__ offs, const int* __restrict__ bsums){
  int i = blockIdx.x*256 + threadIdx.x;
  if (i < NN) offs[i] += bsums[blockIdx.x];
  if (i == 0) offs[NN] = NE;
}

__global__ __launch_bounds__(256) void fill_csr(const int* __restrict__ row, const int* __restrict__ col,
                                                const uint16_t* __restrict__ rank,
                                                const int* __restrict__ offs,
                                                const float* __restrict__ dinv,
                                                uint2* __restrict__ csr_cw){
  int e2 = blockIdx.x*256 + threadIdx.x;
  if (e2 < NE/2){
    int2 r2 = ((const int2*)row)[e2];
    int2 c2 = ((const int2*)col)[e2];
    ushort2 k2 = ((const ushort2*)rank)[e2];
    int p0 = offs[r2.x] + (int)k2.x;
    int p1 = offs[r2.y] + (int)k2.y;
    uint2 v0, v1;
    v0.x = (uint32_t)c2.x;
    v1.x = (uint32_t)c2.y;
    union{float f;uint32_t i;}w0; w0.f = dinv[c2.x]; v0.y = w0.i;
    union{float f;uint32_t i;}w1; w1.f = dinv[c2.y]; v1.y = w1.i;
    csr_cw[p0] = v0;
    csr_cw[p1] = v1;
  }
}

// ---------------- fused layer: Hout(bf16) = relu( (A_norm @ hb) @ W + b ) ----------------
// Block = 16 rows. Phase 1: waves claim rows via LDS ticket (load balance),
// aggregate into padded f32 LDS tile. Phase 2: each wave does 2 n-tiles of the
// 16x128 MFMA (2-term split-A), writes bf16. Hout != hb (other blocks gather hb).

__global__ __launch_bounds__(256) void agg_gemm(const uint32_t* __restrict__ hb,
                                                const int* __restrict__ offs,
                                                const uint2* __restrict__ csr_cw,
                                                const float* __restrict__ dinv,
                                                const uint16_t* __restrict__ Wf,
                                                const float* __restrict__ bias,
                                                uint16_t* __restrict__ Hout){
  __shared__ float lds[16*129];
  __shared__ int ticket;
  const int lane = threadIdx.x & 63;
  const int rbase = blockIdx.x*16;   // NN % 16 == 0, all rows valid
  if (threadIdx.x == 0) ticket = 0;
  __syncthreads();

  // ---- phase 1: dynamic row claim ----
  for (;;){
    int rl;
    if (lane == 0) rl = atomicAdd(&ticket, 1);
    rl = __shfl(rl, 0);
    if (rl >= 16) break;

    const int w = rbase + rl;
    const int s = offs[w], e = offs[w+1];
    const float dr = dinv[w];
    const uint32_t us = hb[(size_t)w*64 + lane];

    float a0=0.f,a1=0.f,b0=0.f,b1=0.f,c0=0.f,c1=0.f,d0=0.f,d1=0.f;
    float e0=0.f,e1=0.f,f0=0.f,f1=0.f,g0=0.f,g1=0.f,h0=0.f,h1=0.f;
    int i = s;
    for (; i + 8 <= e; i += 8){
      uint2 p0=csr_cw[i],  p1=csr_cw[i+1], p2=csr_cw[i+2], p3=csr_cw[i+3];
      uint2 p4=csr_cw[i+4],p5=csr_cw[i+5], p6=csr_cw[i+6], p7=csr_cw[i+7];
      uint32_t u0=hb[(size_t)p0.x*64+lane], u1=hb[(size_t)p1.x*64+lane];
      uint32_t u2=hb[(size_t)p2.x*64+lane], u3=hb[(size_t)p3.x*64+lane];
      uint32_t u4=hb[(size_t)p4.x*64+lane], u5=hb[(size_t)p5.x*64+lane];
      uint32_t u6=hb[(size_t)p6.x*64+lane], u7=hb[(size_t)p7.x*64+lane];
      a0 += u2f(p0.y)*bfu_lo(u0); a1 += u2f(p0.y)*bfu_hi(u0);
      b0 += u2f(p1.y)*bfu_lo(u1); b1 += u2f(p1.y)*bfu_hi(u1);
      c0 += u2f(p2.y)*bfu_lo(u2); c1 += u2f(p2.y)*bfu_hi(u2);
      d0 += u2f(p3.y)*bfu_lo(u3); d1 += u2f(p3.y)*bfu_hi(u3);
      e0 += u2f(p4.y)*bfu_lo(u4); e1 += u2f(p4.y)*bfu_hi(u4);
      f0 += u2f(p5.y)*bfu_lo(u5); f1 += u2f(p5.y)*bfu_hi(u5);
      g0 += u2f(p6.y)*bfu_lo(u6); g1 += u2f(p6.y)*bfu_hi(u6);
      h0 += u2f(p7.y)*bfu_lo(u7); h1 += u2f(p7.y)*bfu_hi(u7);
    }
    if (i + 4 <= e){
      uint2 p0=csr_cw[i], p1=csr_cw[i+1], p2=csr_cw[i+2], p3=csr_cw[i+3];
      uint32_t u0=hb[(size_t)p0.x*64+lane], u1=hb[(size_t)p1.x*64+lane];
      uint32_t u2=hb[(size_t)p2.x*64+lane], u3=hb[(size_t)p3.x*64+lane];
      a0 += u2f(p0.y)*bfu_lo(u0); a1 += u2f(p0.y)*bfu_hi(u0);
      b0 += u2f(p1.y)*bfu_lo(u1); b1 += u2f(p1.y)*bfu_hi(u1);
      c0 += u2f(p2.y)*bfu_lo(u2); c1 += u2f(p2.y)*bfu_hi(u2);
      d0 += u2f(p3.y)*bfu_lo(u3); d1 += u2f(p3.y)*bfu_hi(u3);
      i += 4;
    }
    for (; i < e; ++i){
      uint2 p = csr_cw[i];
      uint32_t u = hb[(size_t)p.x*64 + lane];
      a0 += u2f(p.y)*bfu_lo(u); a1 += u2f(p.y)*bfu_hi(u);
    }
    float r0 = (((a0+b0)+(c0+d0)) + ((e0+f0)+(g0+h0))) + dr*bfu_lo(us);
    float r1 = (((a1+b1)+(c1+d1)) + ((e1+f1)+(g1+h1))) + dr*bfu_hi(us);
    lds[rl*129 + 2*lane]     = r0*dr;
    lds[rl*129 + 2*lane + 1] = r1*dr;
  }
  __syncthreads();

  // ---- phase 2: 16x128 GEMM tile; this wave covers n-tiles 2*wid, 2*wid+1 ----
  const int wid = threadIdx.x >> 6;
  const int mr = lane & 15;
  const int ko = (lane >> 4) << 3;
  float4v acc[2];
  { float4v z = {0.f,0.f,0.f,0.f}; acc[0] = z; acc[1] = z; }
#pragma unroll
  for (int kb = 0; kb < 4; ++kb){
    short8 ah, al;
#pragma unroll
    for (int j = 0; j < 8; ++j){
      float f = lds[mr*129 + kb*32 + ko + j];
      short h, l; split2(f, h, l); ah[j] = h; al[j] = l;
    }
#pragma unroll
    for (int t = 0; t < 2; ++t){
      int nt = wid*2 + t;
      short8 bf = *(const short8*)&Wf[(kb*8 + nt)*512 + lane*8];
      acc[t] = __builtin_amdgcn_mfma_f32_16x16x32_bf16(ah, bf, acc[t], 0, 0, 0);
      acc[t] = __builtin_amdgcn_mfma_f32_16x16x32_bf16(al, bf, acc[t], 0, 0, 0);
    }
  }
  const int col = lane & 15;
  const int rb  = (lane >> 4) * 4;
#pragma unroll
  for (int t = 0; t < 2; ++t){
    int n = (wid*2 + t)*16 + col;
    float bv = bias[n];
#pragma unroll
    for (int r = 0; r < 4; ++r){
      int m = rbase + rb + r;
      float v = acc[t][r] + bv;
      Hout[(size_t)m*128 + n] = f2bf(v > 0.f ? v : 0.f);
    }
  }
}

// ---------------- fused MLP: 2 m-tiles/wave, bf16 weights (1-term), stride-260 LDS ----------------

#define HS 260

__global__ __launch_bounds__(256) void mlp_fused(const uint16_t* __restrict__ Hb,
                                                 const uint16_t* __restrict__ W1f,
                                                 const float* __restrict__ b1,
                                                 const uint16_t* __restrict__ W2f,
                                                 const float* __restrict__ b2,
                                                 float* __restrict__ out, int M){
  __shared__ uint16_t hid[128*HS];
  const int lane = threadIdx.x & 63;
  const int wid = threadIdx.x >> 6;
  const int mbase = blockIdx.x*128 + wid*32;
  const int mr = lane & 15;
  const int a0r = (mbase + mr < M) ? (mbase + mr) : (M-1);
  const int a1r = (mbase + 16 + mr < M) ? (mbase + 16 + mr) : (M-1);
  const int ko = (lane >> 4) << 3;
  const int col = lane & 15;
  const int rb  = (lane >> 4) * 4;

  float4v acc1[16][2];
#pragma unroll
  for (int nt = 0; nt < 16; ++nt){ float4v z = {0.f,0.f,0.f,0.f}; acc1[nt][0] = z; acc1[nt][1] = z; }
#pragma unroll
  for (int kb = 0; kb < 4; ++kb){
    short8 af0 = *(const short8*)&Hb[(size_t)a0r*128 + kb*32 + ko];
    short8 af1 = *(const short8*)&Hb[(size_t)a1r*128 + kb*32 + ko];
#pragma unroll
    for (int nt = 0; nt < 16; ++nt){
      short8 bf = *(const short8*)&W1f[(kb*16 + nt)*512 + lane*8];
      acc1[nt][0] = __builtin_amdgcn_mfma_f32_16x16x32_bf16(af0, bf, acc1[nt][0], 0, 0, 0);
      acc1[nt][1] = __builtin_amdgcn_mfma_f32_16x16x32_bf16(af1, bf, acc1[nt][1], 0, 0, 0);
    }
  }
#pragma unroll
  for (int nt = 0; nt < 16; ++nt){
    float bv = b1[nt*16 + col];
#pragma unroll
    for (int mt = 0; mt < 2; ++mt){
#pragma unroll
      for (int r = 0; r < 4; ++r){
        float v = acc1[nt][mt][r] + bv;
        v = v > 0.f ? v : 0.f;
        hid[(wid*32 + mt*16 + rb + r)*HS + nt*16 + col] = f2bf(v);
      }
    }
  }
  __syncthreads();

  float4v acc2[3][2];
#pragma unroll
  for (int nt = 0; nt < 3; ++nt){ float4v z = {0.f,0.f,0.f,0.f}; acc2[nt][0] = z; acc2[nt][1] = z; }
#pragma unroll
  for (int kb = 0; kb < 8; ++kb){
    short8 a0 = *(const short8*)&hid[(wid*32 + mr)*HS + kb*32 + ko];
    short8 a1 = *(const short8*)&hid[(wid*32 + 16 + mr)*HS + kb*32 + ko];
#pragma unroll
    for (int nt = 0; nt < 3; ++nt){
      short8 bf = *(const short8*)&W2f[(kb*3 + nt)*512 + lane*8];
      acc2[nt][0] = __builtin_amdgcn_mfma_f32_16x16x32_bf16(a0, bf, acc2[nt][0], 0, 0, 0);
      acc2[nt][1] = __builtin_amdgcn_mfma_f32_16x16x32_bf16(a1, bf, acc2[nt][1], 0, 0, 0);
    }
  }
#pragma unroll
  for (int nt = 0; nt < 3; ++nt){
    int n = nt*16 + col;
    if (n < LL){
      float bv = b2[n];
#pragma unroll
      for (int mt = 0; mt < 2; ++mt){
#pragma unroll
        for (int r = 0; r < 4; ++r){
          int m = mbase + mt*16 + rb + r;
          if (m < M) out[(size_t)m*LL + n] = acc2[nt][mt][r] + bv;
        }
      }
    }
  }
}

// ---------------- launch ----------------

extern "C" void kernel_launch(void* const* d_in, const int* in_sizes, int n_in,
                              void* d_out, int out_size, void* d_ws, size_t ws_size,
                              hipStream_t stream){
  const float* x   = (const float*)d_in[0];
  const int*   ei  = (const int*)d_in[1];
  const float* W0  = (const float*)d_in[2];
  const float* b0  = (const float*)d_in[3];
  const float* W1  = (const float*)d_in[4];
  const float* b1  = (const float*)d_in[5];
  const float* W2  = (const float*)d_in[6];
  const float* b2  = (const float*)d_in[7];
  const float* Wm1 = (const float*)d_in[8];
  const float* bm1 = (const float*)d_in[9];
  const float* Wm2 = (const float*)d_in[10];
  const float* bm2 = (const float*)d_in[11];
  const int* row = ei;
  const int* col = ei + NE;

  char* ws = (char*)d_ws;
  size_t off = 0;
  auto alloc = [&](size_t bytes)->void*{
    void* p = ws + off;
    off += (bytes + 255) & ~(size_t)255;
    return p;
  };
  int*      counts  = (int*)alloc((size_t)NN*4);
  int*      offs    = (int*)alloc(((size_t)NN+1)*4);
  int*      bsums   = (int*)alloc(1024*4);
  float*    dinv    = (float*)alloc((size_t)NN*4);
  uint16_t* rank    = (uint16_t*)alloc((size_t)NE*2);
  uint2*    csr_cw  = (uint2*)alloc((size_t)NE*8);
  uint16_t* W0f     = (uint16_t*)alloc(4*8*512*2);
  uint16_t* W1f     = (uint16_t*)alloc(4*8*512*2);
  uint16_t* W2f     = (uint16_t*)alloc(4*8*512*2);
  uint16_t* Wm1f    = (uint16_t*)alloc(4*16*512*2);
  uint16_t* Wm2f    = (uint16_t*)alloc(8*3*512*2);
  uint16_t* hb      = (uint16_t*)alloc((size_t)NN*DD*2);
  uint16_t* hb2     = (uint16_t*)alloc((size_t)NN*DD*2);

  prep<<<(PREP_TOT+255)/256, 256, 0, stream>>>((const float2*)x, counts, (uint32_t*)hb,
                                               W0, W0f, W1, W1f, W2, W2f, Wm1, Wm1f, Wm2, Wm2f);
  count_edges<<<(NE/2+255)/256, 256, 0, stream>>>(row, counts, rank);
  const int NB = (NN+255)/256;
  scan_partial<<<NB, 256, 0, stream>>>(counts, offs, bsums, dinv);
  scan_block<<<1, 512, 0, stream>>>(bsums, NB);
  scan_add<<<NB, 256, 0, stream>>>(offs, bsums);
  fill_csr<<<(NE/2+255)/256, 256, 0, stream>>>(row, col, rank, offs, dinv, csr_cw);

  const int LB = NN/16;   // 6250 blocks, 16 rows each

  agg_gemm<<<LB, 256, 0, stream>>>((const uint32_t*)hb,  offs, csr_cw, dinv, W0f, b0, hb2);
  agg_gemm<<<LB, 256, 0, stream>>>((const uint32_t*)hb2, offs, csr_cw, dinv, W1f, b1, hb);
  agg_gemm<<<LB, 256, 0, stream>>>((const uint32_t*)hb,  offs, csr_cw, dinv, W2f, b2, hb2);

  const int GB128 = (NN + 127)/128;
  mlp_fused<<<GB128, 256, 0, stream>>>(hb2, Wm1f, bm1, Wm2f, bm2, (float*)d_out, NN);
}